// Round 1
// baseline (28.398 us; speedup 1.0000x reference)
//
#include <hip/hip_runtime.h>

#define N 4096
#define BLOCK 256
#define JC 32                 // j-chunks (grid.y)
#define JCHUNK (N / JC)       // 128 j's per chunk

// Kernel 1: dq = p / m, and zero the dp accumulation region.
__global__ void dq_and_zero_kernel(const float* __restrict__ p,
                                   const float* __restrict__ m,
                                   float* __restrict__ out) {
    int t = blockIdx.x * blockDim.x + threadIdx.x;
    if (t < N * 3) {
        out[t] = p[t] / m[t / 3];
        out[N * 3 + t] = 0.0f;
    }
}

// Kernel 2: each thread owns one particle i; block handles a 128-wide j chunk
// staged in LDS. Partial force sums are atomically accumulated into dp.
__global__ __launch_bounds__(BLOCK)
void lj_force_kernel(const float* __restrict__ q, float* __restrict__ dp) {
    __shared__ float sQ[JCHUNK * 3];
    const int i  = blockIdx.x * BLOCK + threadIdx.x;
    const int j0 = blockIdx.y * JCHUNK;

    // cooperative stage of q[j0 .. j0+JCHUNK) into LDS (384 floats)
    for (int idx = threadIdx.x; idx < JCHUNK * 3; idx += BLOCK)
        sQ[idx] = q[j0 * 3 + idx];
    __syncthreads();

    const float qx = q[i * 3 + 0];
    const float qy = q[i * 3 + 1];
    const float qz = q[i * 3 + 2];

    float fx = 0.0f, fy = 0.0f, fz = 0.0f;

    #pragma unroll 4
    for (int jj = 0; jj < JCHUNK; ++jj) {
        const int j = j0 + jj;
        const float dx = qx - sQ[jj * 3 + 0];   // uniform LDS addr -> broadcast
        const float dy = qy - sQ[jj * 3 + 1];
        const float dz = qz - sQ[jj * 3 + 2];
        const float r2 = dx * dx + dy * dy + dz * dz;
        if (j != i) {                            // skip self (r2 == 0)
            const float inv_r2  = 1.0f / r2;
            const float inv_r4  = inv_r2 * inv_r2;
            const float inv_r8  = inv_r4 * inv_r4;
            const float inv_r14 = inv_r8 * inv_r4 * inv_r2;
            // -48 * (r^-14 - 0.5 r^-8); fold sign/scale once
            const float s = -48.0f * (inv_r14 - 0.5f * inv_r8);
            fx = fmaf(s, dx, fx);
            fy = fmaf(s, dy, fy);
            fz = fmaf(s, dz, fz);
        }
    }

    atomicAdd(&dp[i * 3 + 0], fx);
    atomicAdd(&dp[i * 3 + 1], fy);
    atomicAdd(&dp[i * 3 + 2], fz);
}

extern "C" void kernel_launch(void* const* d_in, const int* in_sizes, int n_in,
                              void* d_out, int out_size, void* d_ws, size_t ws_size,
                              hipStream_t stream) {
    const float* q = (const float*)d_in[0];
    const float* p = (const float*)d_in[1];
    const float* m = (const float*)d_in[2];
    float* out = (float*)d_out;

    dq_and_zero_kernel<<<(N * 3 + 255) / 256, 256, 0, stream>>>(p, m, out);

    dim3 grid(N / BLOCK, JC);
    lj_force_kernel<<<grid, BLOCK, 0, stream>>>(q, out + N * 3);
}

// Round 2
// 22.374 us; speedup vs baseline: 1.2692x; 1.2692x over previous
//
#include <hip/hip_runtime.h>

#define N 4096
#define BLOCK 256
#define JC 64                 // j-chunks (grid.y)
#define JCHUNK (N / JC)       // 64 j's per chunk

// Kernel 1: dq = p / m, and zero the dp accumulation region.
__global__ void dq_and_zero_kernel(const float* __restrict__ p,
                                   const float* __restrict__ m,
                                   float* __restrict__ out) {
    int t = blockIdx.x * blockDim.x + threadIdx.x;
    if (t < N * 3) {
        out[t] = p[t] / m[t / 3];
        out[N * 3 + t] = 0.0f;
    }
}

// Per-pair body. j-side positions come from wave-uniform addresses -> the
// compiler emits scalar (s_load) reads through the K-cache; no LDS, no VMEM
// in the inner loop. DIAG=true adds the j==i mask (only 1/16 of blocks).
template <bool DIAG>
__device__ __forceinline__ void lj_accum(const float* __restrict__ qj, int j0, int i,
                                         float qx, float qy, float qz,
                                         float& fx, float& fy, float& fz) {
    #pragma unroll 8
    for (int jj = 0; jj < JCHUNK; ++jj) {
        const float dx = qx - qj[jj * 3 + 0];   // uniform addr -> s_load
        const float dy = qy - qj[jj * 3 + 1];
        const float dz = qz - qj[jj * 3 + 2];
        const float r2 = fmaf(dx, dx, fmaf(dy, dy, dz * dz));
        const float inv_r2  = __builtin_amdgcn_rcpf(r2);   // v_rcp_f32
        const float inv_r4  = inv_r2 * inv_r2;
        const float inv_r8  = inv_r4 * inv_r4;
        const float inv_r14 = inv_r8 * inv_r4 * inv_r2;
        // s = -48*(r^-14 - 0.5 r^-8) = -48*r^-14 + 24*r^-8
        float s = fmaf(-48.0f, inv_r14, 24.0f * inv_r8);
        if (DIAG)
            s = (j0 + jj == i) ? 0.0f : s;      // predicated, no divergence
        fx = fmaf(s, dx, fx);
        fy = fmaf(s, dy, fy);
        fz = fmaf(s, dz, fz);
    }
}

__global__ __launch_bounds__(BLOCK)
void lj_force_kernel(const float* __restrict__ q, float* __restrict__ dp) {
    const int i  = blockIdx.x * BLOCK + threadIdx.x;
    const int j0 = blockIdx.y * JCHUNK;
    const float* __restrict__ qj = q + j0 * 3;

    const float qx = q[i * 3 + 0];
    const float qy = q[i * 3 + 1];
    const float qz = q[i * 3 + 2];

    float fx = 0.0f, fy = 0.0f, fz = 0.0f;

    // diagonal chunk iff [j0, j0+64) intersects [bx*256, bx*256+256)
    if ((blockIdx.y >> 2) == blockIdx.x)
        lj_accum<true >(qj, j0, i, qx, qy, qz, fx, fy, fz);
    else
        lj_accum<false>(qj, j0, i, qx, qy, qz, fx, fy, fz);

    atomicAdd(&dp[i * 3 + 0], fx);
    atomicAdd(&dp[i * 3 + 1], fy);
    atomicAdd(&dp[i * 3 + 2], fz);
}

extern "C" void kernel_launch(void* const* d_in, const int* in_sizes, int n_in,
                              void* d_out, int out_size, void* d_ws, size_t ws_size,
                              hipStream_t stream) {
    const float* q = (const float*)d_in[0];
    const float* p = (const float*)d_in[1];
    const float* m = (const float*)d_in[2];
    float* out = (float*)d_out;

    dq_and_zero_kernel<<<(N * 3 + 255) / 256, 256, 0, stream>>>(p, m, out);

    dim3 grid(N / BLOCK, JC);
    lj_force_kernel<<<grid, BLOCK, 0, stream>>>(q, out + N * 3);
}